// Round 16
// baseline (148.537 us; speedup 1.0000x reference)
//
#include <hip/hip_runtime.h>
#include <hip/hip_bf16.h>
#include <float.h>
#include <stdint.h>

// Problem constants (fixed by setup_inputs): B=4, N=M=4096, D=3.
#define BATCH 4
#define NPTS  4096
#define TOT   (BATCH * NPTS)   // 16384

typedef float v2f __attribute__((ext_vector_type(2)));
typedef float v4f __attribute__((ext_vector_type(4)));

// Stripe scheme: stripe s = {j : j % NS == s}, M = NPTS/NS members each.
template<int NS>
__device__ __forceinline__ int tslot(int n) {
    constexpr int M = NPTS / NS;
    return (n & (NS - 1)) * M + (n / NS);
}

// ---------------------------------------------------------------------------
// Kernel 1: pack points into float4 {x, y, z, |p|^2} + stripe-major transposed
// copy + (optional) pair-SoA copy for the packed round0. Also zeroes the
// last-block-done counter used by the fused normal+final reduction.
// rr is x*x + y*y + z*z left-to-right, matching jnp.sum(x*x, -1).
// ---------------------------------------------------------------------------
template<int NS>
__global__ __launch_bounds__(256) void pack_kernel(
    const float* __restrict__ gts, const float* __restrict__ preds,
    float4* __restrict__ pkG, float4* __restrict__ pkP,
    float4* __restrict__ pkGT, float4* __restrict__ pkPT,
    float* __restrict__ pairG, float* __restrict__ pairP,
    int* __restrict__ counter)
{
    int i = blockIdx.x * blockDim.x + threadIdx.x;   // 0 .. 2*TOT-1
    if (i == 0) *counter = 0;                        // reset for this call
    if (i >= 2 * TOT) return;
    const float* src = (i < TOT) ? gts : preds;
    float4* dst      = (i < TOT) ? pkG : pkP;
    float4* dstT     = (i < TOT) ? pkGT : pkPT;
    float* pairDst   = (i < TOT) ? pairG : pairP;
    int k            = (i < TOT) ? i : i - TOT;
    float x = src[3 * k + 0];
    float y = src[3 * k + 1];
    float z = src[3 * k + 2];
    float rr = __fadd_rn(__fadd_rn(__fmul_rn(x, x), __fmul_rn(y, y)), __fmul_rn(z, z));
    float4 v = make_float4(x, y, z, rr);
    dst[k] = v;
    int b = k >> 12, n = k & (NPTS - 1);
    dstT[(b << 12) + tslot<NS>(n)] = v;
    if (pairDst) {
        int u = n >> 7, l = n & 63, hb = (n >> 6) & 1;
        size_t fb = ((size_t)(b * 2048 + (u << 6) + l)) * 8 + hb;
        pairDst[fb + 0] = x;
        pairDst[fb + 2] = y;
        pairDst[fb + 4] = z;
        pairDst[fb + 6] = rr;
    }
}

// ---------------------------------------------------------------------------
// Round 0, PACKED fp32, ILP version (verified R10/R15: 118 us wall, absmax 64).
// Each v_pk_* op is its own asm statement with SSA operands. Per half:
// zz = ((ox*x)+(oy*y))+(oz*z); s = orr+w; d = fma(-2,zz,s) — exact scalar
// sequence; jA then jB ascending -> strict '<' matches numpy argmin.
// Lane l IS stripe l (NS=64): per-lane minima are the stripe partials.
// ---------------------------------------------------------------------------
__global__ __launch_bounds__(256) void round0_packed(
    const float4* __restrict__ pkG, const float4* __restrict__ pkP,
    const float* __restrict__ pairG, const float* __restrict__ pairP,
    float* __restrict__ dS, int* __restrict__ iS,
    float* __restrict__ dF, int* __restrict__ iF,
    int* __restrict__ iST, int* __restrict__ iFT,
    int2* __restrict__ stripes)   // [2][TOT][64]
{
    int wid  = blockIdx.x * 4 + (threadIdx.x >> 6);   // 0..8191
    int lane = threadIdx.x & 63;
    bool isRow = wid < 4096;
    int w = isRow ? wid : wid - 4096;
    int ownBase = w * 4;                 // 4 | 4096 -> no batch straddle
    int b = ownBase >> 12;
    int obase = b << 12;

    const float4* own = isRow ? pkG : pkP;
    const float* pair = isRow ? pairP : pairG;
    float* dOut = isRow ? dS : dF;
    int*   iOut = isRow ? iS : iF;
    int*   iOutT = isRow ? iST : iFT;
    int dirOfs  = isRow ? 0 : TOT;

    v2f ox2[4], oy2[4], oz2[4], ow2[4];
    #pragma unroll
    for (int r = 0; r < 4; ++r) {
        float4 p = own[ownBase + r];
        ox2[r] = (v2f){p.x, p.x};
        oy2[r] = (v2f){p.y, p.y};
        oz2[r] = (v2f){p.z, p.z};
        ow2[r] = (v2f){p.w, p.w};
    }
    v2f n2 = (v2f){-2.0f, -2.0f};

    float best[4]; int bidx[4];
    #pragma unroll
    for (int r = 0; r < 4; ++r) { best[r] = FLT_MAX; bidx[r] = 0; }

    const v4f* pb = (const v4f*)pair + obase;   // batch b at v4f index obase
    #pragma unroll 2
    for (int u = 0; u < 32; ++u) {
        int pi = (((u << 6) + lane) << 1);
        v4f h0 = pb[pi];
        v4f h1 = pb[pi + 1];
        v2f xab = h0.xy, yab = h0.zw, zab = h1.xy, wab = h1.zw;
        int jA = lane + (u << 7), jB = jA + 64;
        #pragma unroll
        for (int r = 0; r < 4; ++r) {
            v2f t0, t1, t2, s, dd;
            asm("v_pk_mul_f32 %0, %1, %2" : "=v"(t0) : "v"(ox2[r]), "v"(xab));
            asm("v_pk_mul_f32 %0, %1, %2" : "=v"(t1) : "v"(oy2[r]), "v"(yab));
            asm("v_pk_mul_f32 %0, %1, %2" : "=v"(t2) : "v"(oz2[r]), "v"(zab));
            asm("v_pk_add_f32 %0, %1, %2" : "=v"(s)  : "v"(ow2[r]), "v"(wab));
            asm("v_pk_add_f32 %0, %1, %2" : "=v"(t0) : "v"(t0), "v"(t1));
            asm("v_pk_add_f32 %0, %1, %2" : "=v"(t0) : "v"(t0), "v"(t2));
            asm("v_pk_fma_f32 %0, %1, %2, %3" : "=v"(dd) : "v"(n2), "v"(t0), "v"(s));
            float dA = dd.x, dB = dd.y;
            if (dA < best[r]) { best[r] = dA; bidx[r] = jA; }
            if (dB < best[r]) { best[r] = dB; bidx[r] = jB; }
        }
    }

    #pragma unroll
    for (int r = 0; r < 4; ++r) {
        float v = best[r]; int ix = bidx[r];
        stripes[(size_t)(dirOfs + ownBase + r) * 64 + lane] =
            make_int2(__float_as_int(v), ix);
        #pragma unroll
        for (int off = 1; off <= 32; off <<= 1) {
            float v2 = __shfl_xor(v, off);
            int   i2 = __shfl_xor(ix, off);
            if (v2 < v || (v2 == v && i2 < ix)) { v = v2; ix = i2; }
        }
        if (lane == 0) {
            iOut[ownBase + r] = ix;
            dOut[ownBase + r] = v;
            int nl = (ownBase & (NPTS - 1)) + r;
            iOutT[obase + tslot<64>(nl)] = ix;
        }
    }
}

// ---------------------------------------------------------------------------
// Round 0, scalar (verified) — NS=16 tier.
// ---------------------------------------------------------------------------
template<int NS>
__global__ __launch_bounds__(256) void round0_kernel(
    const float4* __restrict__ pkG, const float4* __restrict__ pkP,
    float* __restrict__ dS, int* __restrict__ iS,
    float* __restrict__ dF, int* __restrict__ iF,
    int* __restrict__ iST, int* __restrict__ iFT,
    int2* __restrict__ stripes)
{
    int wid  = blockIdx.x * 4 + (threadIdx.x >> 6);
    int lane = threadIdx.x & 63;
    bool isRow = wid < 4096;
    int w = isRow ? wid : wid - 4096;
    int ownBase = w * 4;
    int b = ownBase >> 12;
    int obase = b << 12;

    const float4* own = isRow ? pkG : pkP;
    const float4* oth = isRow ? pkP : pkG;
    float* dOut = isRow ? dS : dF;
    int*   iOut = isRow ? iS : iF;
    int*   iOutT = isRow ? iST : iFT;
    int dirOfs  = isRow ? 0 : TOT;

    float ox[4], oy[4], oz[4], orr[4];
    #pragma unroll
    for (int r = 0; r < 4; ++r) {
        float4 p = own[ownBase + r];
        ox[r] = p.x; oy[r] = p.y; oz[r] = p.z; orr[r] = p.w;
    }
    float best[4]; int bidx[4];
    #pragma unroll
    for (int r = 0; r < 4; ++r) { best[r] = FLT_MAX; bidx[r] = 0; }

    const float4* qp = oth + obase + lane;
    #pragma unroll 2
    for (int t = 0; t < 64; ++t) {
        float4 q = qp[t * 64];
        int j = lane + (t << 6);
        #pragma unroll
        for (int r = 0; r < 4; ++r) {
            float zz = __fadd_rn(__fadd_rn(__fmul_rn(ox[r], q.x),
                                           __fmul_rn(oy[r], q.y)),
                                 __fmul_rn(oz[r], q.z));
            float d = __fmaf_rn(-2.0f, zz, __fadd_rn(orr[r], q.w));
            if (d < best[r]) { best[r] = d; bidx[r] = j; }
        }
    }

    #pragma unroll
    for (int r = 0; r < 4; ++r) {
        float v = best[r]; int ix = bidx[r];
        #pragma unroll
        for (int off = NS; off <= 32; off <<= 1) {
            float v2 = __shfl_xor(v, off);
            int   i2 = __shfl_xor(ix, off);
            if (v2 < v || (v2 == v && i2 < ix)) { v = v2; ix = i2; }
        }
        if (lane < NS)
            stripes[(size_t)(dirOfs + ownBase + r) * NS + lane] =
                make_int2(__float_as_int(v), ix);
        #pragma unroll
        for (int off = 1; off < NS; off <<= 1) {
            float v2 = __shfl_xor(v, off);
            int   i2 = __shfl_xor(ix, off);
            if (v2 < v || (v2 == v && i2 < ix)) { v = v2; ix = i2; }
        }
        if (lane == 0) {
            iOut[ownBase + r] = ix;
            dOut[ownBase + r] = v;
            int nl = (ownBase & (NPTS - 1)) + r;
            iOutT[obase + tslot<NS>(nl)] = ix;
        }
    }
}

// ---------------------------------------------------------------------------
// Rounds 1-3, incremental stripe invalidation with WRITE-BACK.
// BATCHED: 8 own points per wave (32 per block) — halves the 16 KB exTab
// stagings vs R10's 4/wave and doubles contiguous stripe-key streaming per
// wave. Per-point logic is byte-for-byte the verified R10 logic: check each
// stripe winner against ONLY the newest exclusions (invariant: stored stripe
// entries are exact under E_{R-1}); rescan invalid stripes under the full
// cumulative set; write back.
// ---------------------------------------------------------------------------
template<int R, int NS>
__global__ __launch_bounds__(256) void roundR_kernel(
    const float4* __restrict__ pkG, const float4* __restrict__ pkP,
    const float4* __restrict__ pkGT, const float4* __restrict__ pkPT,
    int2* __restrict__ stripes,
    const int* __restrict__ is0, const int* __restrict__ is1, const int* __restrict__ is2,
    const int* __restrict__ if0, const int* __restrict__ if1, const int* __restrict__ if2,
    const int* __restrict__ is0T, const int* __restrict__ is1T, const int* __restrict__ is2T,
    const int* __restrict__ if0T, const int* __restrict__ if1T, const int* __restrict__ if2T,
    int* __restrict__ iS, int* __restrict__ iF,
    int* __restrict__ iST, int* __restrict__ iFT,
    int do_rows)
{
    constexpr int M = NPTS / NS;      // members per stripe
    constexpr int ITERS = M / 64;     // 64-lane passes per rescan

    __shared__ int exTab[NPTS];       // 16 KB staged newest reverse table

    int lane = threadIdx.x & 63;
    int wave = threadIdx.x >> 6;
    int slot0 = (blockIdx.x * 4 + wave) * 8;   // first own-slot of this wave
    int half = do_rows ? TOT : 0;
    bool isRow = slot0 < half;                 // uniform over the 8 slots
    int i0 = isRow ? slot0 : slot0 - half;     // first own index

    // ---- block-uniform staging (block spans 32 slots: one dir, one batch)
    {
        int bSlot0 = blockIdx.x * 32;
        bool blkRow = do_rows && (bSlot0 < half);
        int iFirst = blkRow ? bSlot0 : bSlot0 - half;
        int stObase = iFirst & ~(NPTS - 1);
        const int* stSrc = (blkRow ? (R == 1 ? if0 : R == 2 ? if1 : if2)
                                   : (R == 1 ? is0 : R == 2 ? is1 : is2)) + stObase;
        const int4* s4 = (const int4*)stSrc;
        int4* t4 = (int4*)exTab;
        #pragma unroll
        for (int k = 0; k < NPTS / 4 / 256; ++k)
            t4[k * 256 + threadIdx.x] = s4[k * 256 + threadIdx.x];
        __syncthreads();
    }

    const float4* ownp = isRow ? pkG : pkP;
    const float4* othT = isRow ? pkPT : pkGT;
    const int* exOwn0 = isRow ? is0 : if0;
    const int* exOwn1 = isRow ? is1 : if1;
    const int* exOwn2 = isRow ? is2 : if2;
    const int* x0 = isRow ? if0T : is0T;     // transposed cumulative reverse
    const int* x1 = isRow ? if1T : is1T;
    const int* x2 = isRow ? if2T : is2T;
    int* iOut  = isRow ? iS : iF;
    int* iOutT = isRow ? iST : iFT;
    int dirOfs = isRow ? 0 : TOT;

    int b = i0 >> 12;
    int obase = b << 12;
    const float4* tp = othT + obase;
    const int* x0b = x0 + obase;
    const int* x1b = x1 + obase;
    const int* x2b = x2 + obase;

    #pragma unroll 1
    for (int p = 0; p < 8; ++p) {
        int i = i0 + p;
        int ownIn = i & (NPTS - 1);

        int e0 = exOwn0[i];
        int e1 = (R > 1) ? exOwn1[i] : -1;
        int e2 = (R > 2) ? exOwn2[i] : -1;
        int eNew = (R == 1) ? e0 : (R == 2) ? e1 : e2;

        int2* myStripes = stripes + (size_t)(dirOfs + i) * NS;

        bool excl = false;
        int2 key = make_int2(0x7F7FFFFF, 0x7FFFFFFF);
        if (lane < NS) {
            key = myStripes[lane];
            int jw = key.y;
            if (jw < NPTS)   // sentinel (all-excluded stripe) never wins/changes
                excl = (jw == eNew) || (exTab[jw] == ownIn);
        }
        unsigned long long mask = __ballot(excl);

        float kd = (lane < NS && !excl) ? __int_as_float(key.x) : FLT_MAX;
        int   kj = (lane < NS && !excl) ? key.y : 0x7FFFFFFF;

        if (mask) {
            float4 pq = ownp[i];
            while (mask) {
                int s = __ffsll(mask) - 1;          // wave-uniform stripe id
                mask &= mask - 1;
                int sb = s * M;
                float rd = FLT_MAX; int rj = 0x7FFFFFFF;
                #pragma unroll
                for (int it = 0; it < ITERS; ++it) {
                    int k = (it << 6) + lane;        // 0..M-1, coalesced
                    int j = s + k * NS;              // original other-index
                    float4 q = tp[sb + k];
                    float zz = __fadd_rn(__fadd_rn(__fmul_rn(pq.x, q.x),
                                                   __fmul_rn(pq.y, q.y)),
                                         __fmul_rn(pq.z, q.z));
                    float d = __fmaf_rn(-2.0f, zz, __fadd_rn(pq.w, q.w));
                    bool ex = (j == e0) || (x0b[sb + k] == ownIn);
                    if (R > 1) ex = ex || (j == e1) || (x1b[sb + k] == ownIn);
                    if (R > 2) ex = ex || (j == e2) || (x2b[sb + k] == ownIn);
                    if (!ex && (d < rd || (d == rd && j < rj))) { rd = d; rj = j; }
                }
                #pragma unroll
                for (int off = 1; off < 64; off <<= 1) {
                    float v2 = __shfl_xor(rd, off);
                    int   i2 = __shfl_xor(rj, off);
                    if (v2 < rd || (v2 == rd && i2 < rj)) { rd = v2; rj = i2; }
                }
                if (lane == s) {
                    kd = rd; kj = rj;
                    myStripes[s] = make_int2(__float_as_int(rd), rj);  // write-back
                }
            }
        }

        #pragma unroll
        for (int off = 1; off < 64; off <<= 1) {
            float v2 = __shfl_xor(kd, off);
            int   i2 = __shfl_xor(kj, off);
            if (v2 < kd || (v2 == kd && i2 < kj)) { kd = v2; kj = i2; }
        }
        if (lane == 0) {
            iOut[i] = kj;
            if (iOutT) iOutT[obase + tslot<NS>(ownIn)] = kj;
        }
    }
}

// ---------------------------------------------------------------------------
// Fallback full-rescan kernel (verified) — used only if ws_size is too small.
// ---------------------------------------------------------------------------
template<int R>
__global__ __launch_bounds__(256) void round_full_kernel(
    const float4* __restrict__ pkG, const float4* __restrict__ pkP,
    const int* __restrict__ is0, const int* __restrict__ is1, const int* __restrict__ is2,
    const int* __restrict__ if0, const int* __restrict__ if1, const int* __restrict__ if2,
    float* __restrict__ dS, int* __restrict__ iS,
    float* __restrict__ dF, int* __restrict__ iF,
    int do_rows)
{
    int half    = do_rows ? (gridDim.x >> 1) : gridDim.x;
    bool isRow  = do_rows && ((int)blockIdx.x < half);
    int dirBlk  = isRow ? blockIdx.x : (blockIdx.x - (do_rows ? half : 0));

    const float4* own = isRow ? pkG : pkP;
    const float4* oth = isRow ? pkP : pkG;
    const int* exOwn0 = isRow ? is0 : if0;
    const int* exOwn1 = isRow ? is1 : if1;
    const int* exOwn2 = isRow ? is2 : if2;
    const int* exOth0 = isRow ? if0 : is0;
    const int* exOth1 = isRow ? if1 : is1;
    const int* exOth2 = isRow ? if2 : is2;
    float* dOut = isRow ? dS : dF;
    int*   iOut = isRow ? iS : iF;

    int lane = threadIdx.x & 63;
    int wave = threadIdx.x >> 6;
    int ownBase = dirBlk * 16 + wave * 4;
    int b = ownBase >> 12;
    int obase = b << 12;

    float ox[4], oy[4], oz[4], orr[4];
    int ownIn[4];
    int oe0[4], oe1[4], oe2[4];
    #pragma unroll
    for (int r = 0; r < 4; ++r) {
        float4 p = own[ownBase + r];
        ox[r] = p.x; oy[r] = p.y; oz[r] = p.z; orr[r] = p.w;
        ownIn[r] = (ownBase & (NPTS - 1)) + r;
        oe0[r] = 0; oe1[r] = 0; oe2[r] = 0;
        if (R > 0) oe0[r] = exOwn0[ownBase + r];
        if (R > 1) oe1[r] = exOwn1[ownBase + r];
        if (R > 2) oe2[r] = exOwn2[ownBase + r];
    }

    float best[4]; int bidx[4];
    #pragma unroll
    for (int r = 0; r < 4; ++r) { best[r] = FLT_MAX; bidx[r] = 0; }

    for (int j = lane; j < NPTS; j += 64) {
        float4 q = oth[obase + j];
        int eo0 = 0, eo1 = 0, eo2 = 0;
        if (R > 0) eo0 = exOth0[obase + j];
        if (R > 1) eo1 = exOth1[obase + j];
        if (R > 2) eo2 = exOth2[obase + j];
        #pragma unroll
        for (int r = 0; r < 4; ++r) {
            float zz = __fadd_rn(__fadd_rn(__fmul_rn(ox[r], q.x),
                                           __fmul_rn(oy[r], q.y)),
                                 __fmul_rn(oz[r], q.z));
            float d = __fmaf_rn(-2.0f, zz, __fadd_rn(orr[r], q.w));
            bool ex = false;
            if (R > 0) ex = ex || (j == oe0[r]) || (eo0 == ownIn[r]);
            if (R > 1) ex = ex || (j == oe1[r]) || (eo1 == ownIn[r]);
            if (R > 2) ex = ex || (j == oe2[r]) || (eo2 == ownIn[r]);
            if (ex) d = FLT_MAX;
            if (d < best[r]) { best[r] = d; bidx[r] = j; }
        }
    }

    #pragma unroll
    for (int r = 0; r < 4; ++r) {
        float v = best[r]; int ix = bidx[r];
        #pragma unroll
        for (int off = 32; off > 0; off >>= 1) {
            float v2 = __shfl_xor(v, off);
            int   i2 = __shfl_xor(ix, off);
            if (v2 < v || (v2 == v && i2 < ix)) { v = v2; ix = i2; }
        }
        if (lane == 0) {
            iOut[ownBase + r] = ix;
            if (dOut) dOut[ownBase + r] = v;
        }
    }
}

// ---------------------------------------------------------------------------
// Per-(batch, segment) partial sums + FUSED final combine.
// 16 blocks write partials; each block's t==0 then does a device-scope
// release (__threadfence) + atomicAdd on `counter`; the LAST block acquires
// (__threadfence) and reduces all 16 partials in fixed order -> out[0].
// Deterministic: the final sum is order-fixed regardless of which block runs
// it. counter is zeroed by pack_kernel earlier in the stream.
// ---------------------------------------------------------------------------
__global__ __launch_bounds__(256) void normal_kernel(
    const float* __restrict__ preds, const float* __restrict__ normals,
    const float* __restrict__ dS, const float* __restrict__ dF,
    const int* __restrict__ if0, const int* __restrict__ if1,
    const int* __restrict__ if2, const int* __restrict__ if3,
    float4* __restrict__ partials, int* __restrict__ counter,
    float* __restrict__ out)
{
    int b   = blockIdx.x >> 2;
    int seg = blockIdx.x & 3;
    int t   = threadIdx.x;

    const float* pp = preds + (size_t)b * NPTS * 3;
    float champ = 0.f, s1 = 0.f, s2 = 0.f, s3 = 0.f;

    for (int it = 0; it < 4; ++it) {
        int m  = seg * 1024 + it * 256 + t;
        int gi = b * NPTS + m;
        champ += dF[gi] + dS[gi];

        int i0 = if0[gi];
        float p0x = pp[3 * i0 + 0], p0y = pp[3 * i0 + 1], p0z = pp[3 * i0 + 2];
        float nx = normals[3 * gi + 0], ny = normals[3 * gi + 1], nz = normals[3 * gi + 2];

        int iA = if1[gi];
        s1 += (p0x - pp[3 * iA + 0]) * nx + (p0y - pp[3 * iA + 1]) * ny + (p0z - pp[3 * iA + 2]) * nz;
        int iB = if2[gi];
        s2 += (p0x - pp[3 * iB + 0]) * nx + (p0y - pp[3 * iB + 1]) * ny + (p0z - pp[3 * iB + 2]) * nz;
        int iC = if3[gi];
        s3 += (p0x - pp[3 * iC + 0]) * nx + (p0y - pp[3 * iC + 1]) * ny + (p0z - pp[3 * iC + 2]) * nz;
    }

    #pragma unroll
    for (int off = 32; off > 0; off >>= 1) {
        champ += __shfl_xor(champ, off);
        s1    += __shfl_xor(s1, off);
        s2    += __shfl_xor(s2, off);
        s3    += __shfl_xor(s3, off);
    }
    __shared__ float4 red[4];
    int wave = t >> 6, lane = t & 63;
    if (lane == 0) red[wave] = make_float4(champ, s1, s2, s3);
    __syncthreads();
    if (t == 0) {
        float4 a = red[0];
        for (int w = 1; w < 4; ++w) {
            a.x += red[w].x; a.y += red[w].y; a.z += red[w].z; a.w += red[w].w;
        }
        partials[blockIdx.x] = a;
        __threadfence();                       // release partials (device scope)
        int prev = atomicAdd(counter, 1);      // device-scope by default
        if (prev == 15) {                      // last block: do the final combine
            __threadfence();                   // acquire all partials
            float ch = 0.f;
            float s[BATCH][3];
            for (int bb = 0; bb < BATCH; ++bb)
                for (int k = 0; k < 3; ++k) s[bb][k] = 0.f;
            for (int blk = 0; blk < 16; ++blk) {
                float4 p = partials[blk];
                int bb = blk >> 2;
                ch      += p.x;
                s[bb][0] += p.y;
                s[bb][1] += p.z;
                s[bb][2] += p.w;
            }
            float nl = 0.f;
            for (int k = 0; k < 3; ++k)
                for (int bb = 0; bb < BATCH; ++bb)
                    nl += fabsf(s[bb][k]);
            out[0] = 1.0f + ch + 10.0f * nl;
        }
    }
}

// ---------------------------------------------------------------------------
// Launch. Tiered by ws_size:
//   NS=64 + pairSoA (~19.9 MB): packed round0, 8-pt-batched roundR <- expected
//   NS=16 (~6.0 MB): scalar round0, 8-pt-batched roundR
//   else: verified full-rescan chain
// ---------------------------------------------------------------------------
extern "C" void kernel_launch(void* const* d_in, const int* in_sizes, int n_in,
                              void* d_out, int out_size, void* d_ws, size_t ws_size,
                              hipStream_t stream) {
    const float* gts     = (const float*)d_in[0];
    const float* preds   = (const float*)d_in[1];
    const float* normals = (const float*)d_in[2];
    float* out = (float*)d_out;

    char* ws = (char*)d_ws;
    float4* pkG  = (float4*)ws;
    float4* pkP  = (float4*)(ws + 262144);
    float4* pkGT = (float4*)(ws + 524288);
    float4* pkPT = (float4*)(ws + 786432);
    int* iS0 = (int*)(ws + 1048576);
    int* iS1 = iS0 + TOT;
    int* iS2 = iS1 + TOT;
    int* iF0 = iS2 + TOT;
    int* iF1 = iF0 + TOT;
    int* iF2 = iF1 + TOT;
    int* iF3 = iF2 + TOT;
    float* dS0 = (float*)(iF3 + TOT);
    float* dF0 = dS0 + TOT;
    float4* partials = (float4*)(dF0 + TOT);
    int* iS0T = (int*)((char*)partials + 256);
    int* iS1T = iS0T + TOT;
    int* iS2T = iS1T + TOT;
    int* iF0T = iS2T + TOT;
    int* iF1T = iF0T + TOT;
    int* iF2T = iF1T + TOT;
    size_t stripeOfs = (size_t)((char*)(iF2T + TOT) - ws);  // ~2.03 MB, aligned
    int2* stripes = (int2*)(ws + stripeOfs);
    size_t pairOfs = stripeOfs + (size_t)2 * TOT * 64 * sizeof(int2);
    float* pairG = (float*)(ws + pairOfs);
    float* pairP = pairG + (size_t)TOT * 8;
    size_t ctrOfs = pairOfs + (size_t)2 * TOT * 8 * sizeof(float);
    int* counter = (int*)(ws + ctrOfs);
    size_t need64 = ctrOfs + 256;                                        // ~19.9 MB
    size_t need16 = stripeOfs + (size_t)2 * TOT * 16 * sizeof(int2) + 256; // ~6.0 MB

    if (ws_size >= need64) {
        pack_kernel<64><<<(2 * TOT + 255) / 256, 256, 0, stream>>>(
            gts, preds, pkG, pkP, pkGT, pkPT, pairG, pairP, counter);
        round0_packed<<<2048, 256, 0, stream>>>(pkG, pkP, pairG, pairP,
            dS0, iS0, dF0, iF0, iS0T, iF0T, stripes);
        // batched roundR: 32 own-slots per block
        roundR_kernel<1, 64><<<1024, 256, 0, stream>>>(pkG, pkP, pkGT, pkPT, stripes,
            iS0, iS1, iS2, iF0, iF1, iF2,
            iS0T, iS1T, iS2T, iF0T, iF1T, iF2T,
            iS1, iF1, iS1T, iF1T, 1);
        roundR_kernel<2, 64><<<1024, 256, 0, stream>>>(pkG, pkP, pkGT, pkPT, stripes,
            iS0, iS1, iS2, iF0, iF1, iF2,
            iS0T, iS1T, iS2T, iF0T, iF1T, iF2T,
            iS2, iF2, iS2T, iF2T, 1);
        roundR_kernel<3, 64><<<512, 256, 0, stream>>>(pkG, pkP, pkGT, pkPT, stripes,
            iS0, iS1, iS2, iF0, iF1, iF2,
            iS0T, iS1T, iS2T, iF0T, iF1T, iF2T,
            nullptr, iF3, nullptr, nullptr, 0);
    } else if (ws_size >= need16) {
        pack_kernel<16><<<(2 * TOT + 255) / 256, 256, 0, stream>>>(
            gts, preds, pkG, pkP, pkGT, pkPT, nullptr, nullptr, counter);
        round0_kernel<16><<<2048, 256, 0, stream>>>(pkG, pkP, dS0, iS0, dF0, iF0,
                                                    iS0T, iF0T, stripes);
        roundR_kernel<1, 16><<<1024, 256, 0, stream>>>(pkG, pkP, pkGT, pkPT, stripes,
            iS0, iS1, iS2, iF0, iF1, iF2,
            iS0T, iS1T, iS2T, iF0T, iF1T, iF2T,
            iS1, iF1, iS1T, iF1T, 1);
        roundR_kernel<2, 16><<<1024, 256, 0, stream>>>(pkG, pkP, pkGT, pkPT, stripes,
            iS0, iS1, iS2, iF0, iF1, iF2,
            iS0T, iS1T, iS2T, iF0T, iF1T, iF2T,
            iS2, iF2, iS2T, iF2T, 1);
        roundR_kernel<3, 16><<<512, 256, 0, stream>>>(pkG, pkP, pkGT, pkPT, stripes,
            iS0, iS1, iS2, iF0, iF1, iF2,
            iS0T, iS1T, iS2T, iF0T, iF1T, iF2T,
            nullptr, iF3, nullptr, nullptr, 0);
    } else {
        pack_kernel<64><<<(2 * TOT + 255) / 256, 256, 0, stream>>>(
            gts, preds, pkG, pkP, pkGT, pkPT, nullptr, nullptr, counter);
        round_full_kernel<0><<<2048, 256, 0, stream>>>(pkG, pkP,
            nullptr, nullptr, nullptr, nullptr, nullptr, nullptr,
            dS0, iS0, dF0, iF0, 1);
        round_full_kernel<1><<<2048, 256, 0, stream>>>(pkG, pkP,
            iS0, nullptr, nullptr, iF0, nullptr, nullptr,
            nullptr, iS1, nullptr, iF1, 1);
        round_full_kernel<2><<<2048, 256, 0, stream>>>(pkG, pkP,
            iS0, iS1, nullptr, iF0, iF1, nullptr,
            nullptr, iS2, nullptr, iF2, 1);
        round_full_kernel<3><<<1024, 256, 0, stream>>>(pkG, pkP,
            iS0, iS1, iS2, iF0, iF1, iF2,
            nullptr, nullptr, nullptr, iF3, 0);
    }

    normal_kernel<<<16, 256, 0, stream>>>(preds, normals, dS0, dF0,
                                          iF0, iF1, iF2, iF3,
                                          partials, counter, out);
}

// Round 17
// 117.823 us; speedup vs baseline: 1.2607x; 1.2607x over previous
//
#include <hip/hip_runtime.h>
#include <hip/hip_bf16.h>
#include <float.h>
#include <stdint.h>

// Problem constants (fixed by setup_inputs): B=4, N=M=4096, D=3.
#define BATCH 4
#define NPTS  4096
#define TOT   (BATCH * NPTS)   // 16384

typedef float v2f __attribute__((ext_vector_type(2)));
typedef float v4f __attribute__((ext_vector_type(4)));

// Stripe scheme: stripe s = {j : j % NS == s}, M = NPTS/NS members each.
template<int NS>
__device__ __forceinline__ int tslot(int n) {
    constexpr int M = NPTS / NS;
    return (n & (NS - 1)) * M + (n / NS);
}

// ---------------------------------------------------------------------------
// Kernel 1: pack points into float4 {x, y, z, |p|^2} + stripe-major transposed
// copy + (optional) pair-SoA copy for the packed round0. Also zeroes the
// last-block-done counter used by the fused normal+final reduction.
// rr is x*x + y*y + z*z left-to-right, matching jnp.sum(x*x, -1).
// ---------------------------------------------------------------------------
template<int NS>
__global__ __launch_bounds__(256) void pack_kernel(
    const float* __restrict__ gts, const float* __restrict__ preds,
    float4* __restrict__ pkG, float4* __restrict__ pkP,
    float4* __restrict__ pkGT, float4* __restrict__ pkPT,
    float* __restrict__ pairG, float* __restrict__ pairP,
    int* __restrict__ counter)
{
    int i = blockIdx.x * blockDim.x + threadIdx.x;   // 0 .. 2*TOT-1
    if (i == 0) *counter = 0;                        // reset for this call
    if (i >= 2 * TOT) return;
    const float* src = (i < TOT) ? gts : preds;
    float4* dst      = (i < TOT) ? pkG : pkP;
    float4* dstT     = (i < TOT) ? pkGT : pkPT;
    float* pairDst   = (i < TOT) ? pairG : pairP;
    int k            = (i < TOT) ? i : i - TOT;
    float x = src[3 * k + 0];
    float y = src[3 * k + 1];
    float z = src[3 * k + 2];
    float rr = __fadd_rn(__fadd_rn(__fmul_rn(x, x), __fmul_rn(y, y)), __fmul_rn(z, z));
    float4 v = make_float4(x, y, z, rr);
    dst[k] = v;
    int b = k >> 12, n = k & (NPTS - 1);
    dstT[(b << 12) + tslot<NS>(n)] = v;
    if (pairDst) {
        int u = n >> 7, l = n & 63, hb = (n >> 6) & 1;
        size_t fb = ((size_t)(b * 2048 + (u << 6) + l)) * 8 + hb;
        pairDst[fb + 0] = x;
        pairDst[fb + 2] = y;
        pairDst[fb + 4] = z;
        pairDst[fb + 6] = rr;
    }
}

// ---------------------------------------------------------------------------
// Round 0, PACKED fp32, ILP version (verified R10/R15: ~118 us wall, absmax 64).
// Each v_pk_* op is its own asm statement with SSA operands. Per half:
// zz = ((ox*x)+(oy*y))+(oz*z); s = orr+w; d = fma(-2,zz,s) — exact scalar
// sequence; jA then jB ascending -> strict '<' matches numpy argmin.
// Lane l IS stripe l (NS=64): per-lane minima are the stripe partials.
// ---------------------------------------------------------------------------
__global__ __launch_bounds__(256) void round0_packed(
    const float4* __restrict__ pkG, const float4* __restrict__ pkP,
    const float* __restrict__ pairG, const float* __restrict__ pairP,
    float* __restrict__ dS, int* __restrict__ iS,
    float* __restrict__ dF, int* __restrict__ iF,
    int* __restrict__ iST, int* __restrict__ iFT,
    int2* __restrict__ stripes)   // [2][TOT][64]
{
    int wid  = blockIdx.x * 4 + (threadIdx.x >> 6);   // 0..8191
    int lane = threadIdx.x & 63;
    bool isRow = wid < 4096;
    int w = isRow ? wid : wid - 4096;
    int ownBase = w * 4;                 // 4 | 4096 -> no batch straddle
    int b = ownBase >> 12;
    int obase = b << 12;

    const float4* own = isRow ? pkG : pkP;
    const float* pair = isRow ? pairP : pairG;
    float* dOut = isRow ? dS : dF;
    int*   iOut = isRow ? iS : iF;
    int*   iOutT = isRow ? iST : iFT;
    int dirOfs  = isRow ? 0 : TOT;

    v2f ox2[4], oy2[4], oz2[4], ow2[4];
    #pragma unroll
    for (int r = 0; r < 4; ++r) {
        float4 p = own[ownBase + r];
        ox2[r] = (v2f){p.x, p.x};
        oy2[r] = (v2f){p.y, p.y};
        oz2[r] = (v2f){p.z, p.z};
        ow2[r] = (v2f){p.w, p.w};
    }
    v2f n2 = (v2f){-2.0f, -2.0f};

    float best[4]; int bidx[4];
    #pragma unroll
    for (int r = 0; r < 4; ++r) { best[r] = FLT_MAX; bidx[r] = 0; }

    const v4f* pb = (const v4f*)pair + obase;   // batch b at v4f index obase
    #pragma unroll 2
    for (int u = 0; u < 32; ++u) {
        int pi = (((u << 6) + lane) << 1);
        v4f h0 = pb[pi];
        v4f h1 = pb[pi + 1];
        v2f xab = h0.xy, yab = h0.zw, zab = h1.xy, wab = h1.zw;
        int jA = lane + (u << 7), jB = jA + 64;
        #pragma unroll
        for (int r = 0; r < 4; ++r) {
            v2f t0, t1, t2, s, dd;
            asm("v_pk_mul_f32 %0, %1, %2" : "=v"(t0) : "v"(ox2[r]), "v"(xab));
            asm("v_pk_mul_f32 %0, %1, %2" : "=v"(t1) : "v"(oy2[r]), "v"(yab));
            asm("v_pk_mul_f32 %0, %1, %2" : "=v"(t2) : "v"(oz2[r]), "v"(zab));
            asm("v_pk_add_f32 %0, %1, %2" : "=v"(s)  : "v"(ow2[r]), "v"(wab));
            asm("v_pk_add_f32 %0, %1, %2" : "=v"(t0) : "v"(t0), "v"(t1));
            asm("v_pk_add_f32 %0, %1, %2" : "=v"(t0) : "v"(t0), "v"(t2));
            asm("v_pk_fma_f32 %0, %1, %2, %3" : "=v"(dd) : "v"(n2), "v"(t0), "v"(s));
            float dA = dd.x, dB = dd.y;
            if (dA < best[r]) { best[r] = dA; bidx[r] = jA; }
            if (dB < best[r]) { best[r] = dB; bidx[r] = jB; }
        }
    }

    #pragma unroll
    for (int r = 0; r < 4; ++r) {
        float v = best[r]; int ix = bidx[r];
        stripes[(size_t)(dirOfs + ownBase + r) * 64 + lane] =
            make_int2(__float_as_int(v), ix);
        #pragma unroll
        for (int off = 1; off <= 32; off <<= 1) {
            float v2 = __shfl_xor(v, off);
            int   i2 = __shfl_xor(ix, off);
            if (v2 < v || (v2 == v && i2 < ix)) { v = v2; ix = i2; }
        }
        if (lane == 0) {
            iOut[ownBase + r] = ix;
            dOut[ownBase + r] = v;
            int nl = (ownBase & (NPTS - 1)) + r;
            iOutT[obase + tslot<64>(nl)] = ix;
        }
    }
}

// ---------------------------------------------------------------------------
// Round 0, scalar (verified) — NS=16 tier.
// ---------------------------------------------------------------------------
template<int NS>
__global__ __launch_bounds__(256) void round0_kernel(
    const float4* __restrict__ pkG, const float4* __restrict__ pkP,
    float* __restrict__ dS, int* __restrict__ iS,
    float* __restrict__ dF, int* __restrict__ iF,
    int* __restrict__ iST, int* __restrict__ iFT,
    int2* __restrict__ stripes)
{
    int wid  = blockIdx.x * 4 + (threadIdx.x >> 6);
    int lane = threadIdx.x & 63;
    bool isRow = wid < 4096;
    int w = isRow ? wid : wid - 4096;
    int ownBase = w * 4;
    int b = ownBase >> 12;
    int obase = b << 12;

    const float4* own = isRow ? pkG : pkP;
    const float4* oth = isRow ? pkP : pkG;
    float* dOut = isRow ? dS : dF;
    int*   iOut = isRow ? iS : iF;
    int*   iOutT = isRow ? iST : iFT;
    int dirOfs  = isRow ? 0 : TOT;

    float ox[4], oy[4], oz[4], orr[4];
    #pragma unroll
    for (int r = 0; r < 4; ++r) {
        float4 p = own[ownBase + r];
        ox[r] = p.x; oy[r] = p.y; oz[r] = p.z; orr[r] = p.w;
    }
    float best[4]; int bidx[4];
    #pragma unroll
    for (int r = 0; r < 4; ++r) { best[r] = FLT_MAX; bidx[r] = 0; }

    const float4* qp = oth + obase + lane;
    #pragma unroll 2
    for (int t = 0; t < 64; ++t) {
        float4 q = qp[t * 64];
        int j = lane + (t << 6);
        #pragma unroll
        for (int r = 0; r < 4; ++r) {
            float zz = __fadd_rn(__fadd_rn(__fmul_rn(ox[r], q.x),
                                           __fmul_rn(oy[r], q.y)),
                                 __fmul_rn(oz[r], q.z));
            float d = __fmaf_rn(-2.0f, zz, __fadd_rn(orr[r], q.w));
            if (d < best[r]) { best[r] = d; bidx[r] = j; }
        }
    }

    #pragma unroll
    for (int r = 0; r < 4; ++r) {
        float v = best[r]; int ix = bidx[r];
        #pragma unroll
        for (int off = NS; off <= 32; off <<= 1) {
            float v2 = __shfl_xor(v, off);
            int   i2 = __shfl_xor(ix, off);
            if (v2 < v || (v2 == v && i2 < ix)) { v = v2; ix = i2; }
        }
        if (lane < NS)
            stripes[(size_t)(dirOfs + ownBase + r) * NS + lane] =
                make_int2(__float_as_int(v), ix);
        #pragma unroll
        for (int off = 1; off < NS; off <<= 1) {
            float v2 = __shfl_xor(v, off);
            int   i2 = __shfl_xor(ix, off);
            if (v2 < v || (v2 == v && i2 < ix)) { v = v2; ix = i2; }
        }
        if (lane == 0) {
            iOut[ownBase + r] = ix;
            dOut[ownBase + r] = v;
            int nl = (ownBase & (NPTS - 1)) + r;
            iOutT[obase + tslot<NS>(nl)] = ix;
        }
    }
}

// ---------------------------------------------------------------------------
// Rounds 1-3, incremental stripe invalidation with WRITE-BACK.
// BATCHED: 4 own points per wave (16 per block) — the VERIFIED R10/R15 shape
// (8/wave regressed +10 us/dispatch in R16: halved TLP on a latency-bound
// kernel). Per-point logic: check each stripe winner against ONLY the newest
// exclusions (invariant: stored stripe entries are exact under E_{R-1});
// rescan invalid stripes under the full cumulative set; write back.
// ---------------------------------------------------------------------------
template<int R, int NS>
__global__ __launch_bounds__(256) void roundR_kernel(
    const float4* __restrict__ pkG, const float4* __restrict__ pkP,
    const float4* __restrict__ pkGT, const float4* __restrict__ pkPT,
    int2* __restrict__ stripes,
    const int* __restrict__ is0, const int* __restrict__ is1, const int* __restrict__ is2,
    const int* __restrict__ if0, const int* __restrict__ if1, const int* __restrict__ if2,
    const int* __restrict__ is0T, const int* __restrict__ is1T, const int* __restrict__ is2T,
    const int* __restrict__ if0T, const int* __restrict__ if1T, const int* __restrict__ if2T,
    int* __restrict__ iS, int* __restrict__ iF,
    int* __restrict__ iST, int* __restrict__ iFT,
    int do_rows)
{
    constexpr int M = NPTS / NS;      // members per stripe
    constexpr int ITERS = M / 64;     // 64-lane passes per rescan

    __shared__ int exTab[NPTS];       // 16 KB staged newest reverse table

    int lane = threadIdx.x & 63;
    int wave = threadIdx.x >> 6;
    int slot0 = (blockIdx.x * 4 + wave) * 4;   // first own-slot of this wave
    int half = do_rows ? TOT : 0;
    bool isRow = slot0 < half;                 // uniform over the 4 slots
    int i0 = isRow ? slot0 : slot0 - half;     // first own index

    // ---- block-uniform staging (block spans 16 slots: one dir, one batch)
    {
        int bSlot0 = blockIdx.x * 16;
        bool blkRow = do_rows && (bSlot0 < half);
        int iFirst = blkRow ? bSlot0 : bSlot0 - half;
        int stObase = iFirst & ~(NPTS - 1);
        const int* stSrc = (blkRow ? (R == 1 ? if0 : R == 2 ? if1 : if2)
                                   : (R == 1 ? is0 : R == 2 ? is1 : is2)) + stObase;
        const int4* s4 = (const int4*)stSrc;
        int4* t4 = (int4*)exTab;
        #pragma unroll
        for (int k = 0; k < NPTS / 4 / 256; ++k)
            t4[k * 256 + threadIdx.x] = s4[k * 256 + threadIdx.x];
        __syncthreads();
    }

    const float4* ownp = isRow ? pkG : pkP;
    const float4* othT = isRow ? pkPT : pkGT;
    const int* exOwn0 = isRow ? is0 : if0;
    const int* exOwn1 = isRow ? is1 : if1;
    const int* exOwn2 = isRow ? is2 : if2;
    const int* x0 = isRow ? if0T : is0T;     // transposed cumulative reverse
    const int* x1 = isRow ? if1T : is1T;
    const int* x2 = isRow ? if2T : is2T;
    int* iOut  = isRow ? iS : iF;
    int* iOutT = isRow ? iST : iFT;
    int dirOfs = isRow ? 0 : TOT;

    int b = i0 >> 12;
    int obase = b << 12;
    const float4* tp = othT + obase;
    const int* x0b = x0 + obase;
    const int* x1b = x1 + obase;
    const int* x2b = x2 + obase;

    #pragma unroll 1
    for (int p = 0; p < 4; ++p) {
        int i = i0 + p;
        int ownIn = i & (NPTS - 1);

        int e0 = exOwn0[i];
        int e1 = (R > 1) ? exOwn1[i] : -1;
        int e2 = (R > 2) ? exOwn2[i] : -1;
        int eNew = (R == 1) ? e0 : (R == 2) ? e1 : e2;

        int2* myStripes = stripes + (size_t)(dirOfs + i) * NS;

        bool excl = false;
        int2 key = make_int2(0x7F7FFFFF, 0x7FFFFFFF);
        if (lane < NS) {
            key = myStripes[lane];
            int jw = key.y;
            if (jw < NPTS)   // sentinel (all-excluded stripe) never wins/changes
                excl = (jw == eNew) || (exTab[jw] == ownIn);
        }
        unsigned long long mask = __ballot(excl);

        float kd = (lane < NS && !excl) ? __int_as_float(key.x) : FLT_MAX;
        int   kj = (lane < NS && !excl) ? key.y : 0x7FFFFFFF;

        if (mask) {
            float4 pq = ownp[i];
            while (mask) {
                int s = __ffsll(mask) - 1;          // wave-uniform stripe id
                mask &= mask - 1;
                int sb = s * M;
                float rd = FLT_MAX; int rj = 0x7FFFFFFF;
                #pragma unroll
                for (int it = 0; it < ITERS; ++it) {
                    int k = (it << 6) + lane;        // 0..M-1, coalesced
                    int j = s + k * NS;              // original other-index
                    float4 q = tp[sb + k];
                    float zz = __fadd_rn(__fadd_rn(__fmul_rn(pq.x, q.x),
                                                   __fmul_rn(pq.y, q.y)),
                                         __fmul_rn(pq.z, q.z));
                    float d = __fmaf_rn(-2.0f, zz, __fadd_rn(pq.w, q.w));
                    bool ex = (j == e0) || (x0b[sb + k] == ownIn);
                    if (R > 1) ex = ex || (j == e1) || (x1b[sb + k] == ownIn);
                    if (R > 2) ex = ex || (j == e2) || (x2b[sb + k] == ownIn);
                    if (!ex && (d < rd || (d == rd && j < rj))) { rd = d; rj = j; }
                }
                #pragma unroll
                for (int off = 1; off < 64; off <<= 1) {
                    float v2 = __shfl_xor(rd, off);
                    int   i2 = __shfl_xor(rj, off);
                    if (v2 < rd || (v2 == rd && i2 < rj)) { rd = v2; rj = i2; }
                }
                if (lane == s) {
                    kd = rd; kj = rj;
                    myStripes[s] = make_int2(__float_as_int(rd), rj);  // write-back
                }
            }
        }

        #pragma unroll
        for (int off = 1; off < 64; off <<= 1) {
            float v2 = __shfl_xor(kd, off);
            int   i2 = __shfl_xor(kj, off);
            if (v2 < kd || (v2 == kd && i2 < kj)) { kd = v2; kj = i2; }
        }
        if (lane == 0) {
            iOut[i] = kj;
            if (iOutT) iOutT[obase + tslot<NS>(ownIn)] = kj;
        }
    }
}

// ---------------------------------------------------------------------------
// Fallback full-rescan kernel (verified) — used only if ws_size is too small.
// ---------------------------------------------------------------------------
template<int R>
__global__ __launch_bounds__(256) void round_full_kernel(
    const float4* __restrict__ pkG, const float4* __restrict__ pkP,
    const int* __restrict__ is0, const int* __restrict__ is1, const int* __restrict__ is2,
    const int* __restrict__ if0, const int* __restrict__ if1, const int* __restrict__ if2,
    float* __restrict__ dS, int* __restrict__ iS,
    float* __restrict__ dF, int* __restrict__ iF,
    int do_rows)
{
    int half    = do_rows ? (gridDim.x >> 1) : gridDim.x;
    bool isRow  = do_rows && ((int)blockIdx.x < half);
    int dirBlk  = isRow ? blockIdx.x : (blockIdx.x - (do_rows ? half : 0));

    const float4* own = isRow ? pkG : pkP;
    const float4* oth = isRow ? pkP : pkG;
    const int* exOwn0 = isRow ? is0 : if0;
    const int* exOwn1 = isRow ? is1 : if1;
    const int* exOwn2 = isRow ? is2 : if2;
    const int* exOth0 = isRow ? if0 : is0;
    const int* exOth1 = isRow ? if1 : is1;
    const int* exOth2 = isRow ? if2 : is2;
    float* dOut = isRow ? dS : dF;
    int*   iOut = isRow ? iS : iF;

    int lane = threadIdx.x & 63;
    int wave = threadIdx.x >> 6;
    int ownBase = dirBlk * 16 + wave * 4;
    int b = ownBase >> 12;
    int obase = b << 12;

    float ox[4], oy[4], oz[4], orr[4];
    int ownIn[4];
    int oe0[4], oe1[4], oe2[4];
    #pragma unroll
    for (int r = 0; r < 4; ++r) {
        float4 p = own[ownBase + r];
        ox[r] = p.x; oy[r] = p.y; oz[r] = p.z; orr[r] = p.w;
        ownIn[r] = (ownBase & (NPTS - 1)) + r;
        oe0[r] = 0; oe1[r] = 0; oe2[r] = 0;
        if (R > 0) oe0[r] = exOwn0[ownBase + r];
        if (R > 1) oe1[r] = exOwn1[ownBase + r];
        if (R > 2) oe2[r] = exOwn2[ownBase + r];
    }

    float best[4]; int bidx[4];
    #pragma unroll
    for (int r = 0; r < 4; ++r) { best[r] = FLT_MAX; bidx[r] = 0; }

    for (int j = lane; j < NPTS; j += 64) {
        float4 q = oth[obase + j];
        int eo0 = 0, eo1 = 0, eo2 = 0;
        if (R > 0) eo0 = exOth0[obase + j];
        if (R > 1) eo1 = exOth1[obase + j];
        if (R > 2) eo2 = exOth2[obase + j];
        #pragma unroll
        for (int r = 0; r < 4; ++r) {
            float zz = __fadd_rn(__fadd_rn(__fmul_rn(ox[r], q.x),
                                           __fmul_rn(oy[r], q.y)),
                                 __fmul_rn(oz[r], q.z));
            float d = __fmaf_rn(-2.0f, zz, __fadd_rn(orr[r], q.w));
            bool ex = false;
            if (R > 0) ex = ex || (j == oe0[r]) || (eo0 == ownIn[r]);
            if (R > 1) ex = ex || (j == oe1[r]) || (eo1 == ownIn[r]);
            if (R > 2) ex = ex || (j == oe2[r]) || (eo2 == ownIn[r]);
            if (ex) d = FLT_MAX;
            if (d < best[r]) { best[r] = d; bidx[r] = j; }
        }
    }

    #pragma unroll
    for (int r = 0; r < 4; ++r) {
        float v = best[r]; int ix = bidx[r];
        #pragma unroll
        for (int off = 32; off > 0; off >>= 1) {
            float v2 = __shfl_xor(v, off);
            int   i2 = __shfl_xor(ix, off);
            if (v2 < v || (v2 == v && i2 < ix)) { v = v2; ix = i2; }
        }
        if (lane == 0) {
            iOut[ownBase + r] = ix;
            if (dOut) dOut[ownBase + r] = v;
        }
    }
}

// ---------------------------------------------------------------------------
// Per-(batch, segment) partial sums + FUSED final combine (verified R16:
// passed, absmax 64). 16 blocks write partials; each block's t==0 does a
// device-scope release (__threadfence) + atomicAdd on `counter`; the LAST
// block acquires (__threadfence) and reduces all 16 partials in fixed order
// -> out[0]. Deterministic regardless of which block finishes last.
// counter is zeroed by pack_kernel earlier in the stream.
// ---------------------------------------------------------------------------
__global__ __launch_bounds__(256) void normal_kernel(
    const float* __restrict__ preds, const float* __restrict__ normals,
    const float* __restrict__ dS, const float* __restrict__ dF,
    const int* __restrict__ if0, const int* __restrict__ if1,
    const int* __restrict__ if2, const int* __restrict__ if3,
    float4* __restrict__ partials, int* __restrict__ counter,
    float* __restrict__ out)
{
    int b   = blockIdx.x >> 2;
    int seg = blockIdx.x & 3;
    int t   = threadIdx.x;

    const float* pp = preds + (size_t)b * NPTS * 3;
    float champ = 0.f, s1 = 0.f, s2 = 0.f, s3 = 0.f;

    for (int it = 0; it < 4; ++it) {
        int m  = seg * 1024 + it * 256 + t;
        int gi = b * NPTS + m;
        champ += dF[gi] + dS[gi];

        int i0 = if0[gi];
        float p0x = pp[3 * i0 + 0], p0y = pp[3 * i0 + 1], p0z = pp[3 * i0 + 2];
        float nx = normals[3 * gi + 0], ny = normals[3 * gi + 1], nz = normals[3 * gi + 2];

        int iA = if1[gi];
        s1 += (p0x - pp[3 * iA + 0]) * nx + (p0y - pp[3 * iA + 1]) * ny + (p0z - pp[3 * iA + 2]) * nz;
        int iB = if2[gi];
        s2 += (p0x - pp[3 * iB + 0]) * nx + (p0y - pp[3 * iB + 1]) * ny + (p0z - pp[3 * iB + 2]) * nz;
        int iC = if3[gi];
        s3 += (p0x - pp[3 * iC + 0]) * nx + (p0y - pp[3 * iC + 1]) * ny + (p0z - pp[3 * iC + 2]) * nz;
    }

    #pragma unroll
    for (int off = 32; off > 0; off >>= 1) {
        champ += __shfl_xor(champ, off);
        s1    += __shfl_xor(s1, off);
        s2    += __shfl_xor(s2, off);
        s3    += __shfl_xor(s3, off);
    }
    __shared__ float4 red[4];
    int wave = t >> 6, lane = t & 63;
    if (lane == 0) red[wave] = make_float4(champ, s1, s2, s3);
    __syncthreads();
    if (t == 0) {
        float4 a = red[0];
        for (int w = 1; w < 4; ++w) {
            a.x += red[w].x; a.y += red[w].y; a.z += red[w].z; a.w += red[w].w;
        }
        partials[blockIdx.x] = a;
        __threadfence();                       // release partials (device scope)
        int prev = atomicAdd(counter, 1);      // device-scope by default
        if (prev == 15) {                      // last block: do the final combine
            __threadfence();                   // acquire all partials
            float ch = 0.f;
            float s[BATCH][3];
            for (int bb = 0; bb < BATCH; ++bb)
                for (int k = 0; k < 3; ++k) s[bb][k] = 0.f;
            for (int blk = 0; blk < 16; ++blk) {
                float4 p = partials[blk];
                int bb = blk >> 2;
                ch      += p.x;
                s[bb][0] += p.y;
                s[bb][1] += p.z;
                s[bb][2] += p.w;
            }
            float nl = 0.f;
            for (int k = 0; k < 3; ++k)
                for (int bb = 0; bb < BATCH; ++bb)
                    nl += fabsf(s[bb][k]);
            out[0] = 1.0f + ch + 10.0f * nl;
        }
    }
}

// ---------------------------------------------------------------------------
// Launch. Tiered by ws_size:
//   NS=64 + pairSoA (~19.9 MB): packed round0, 4-pt roundR  <- expected
//   NS=16 (~6.0 MB): scalar round0, 4-pt roundR
//   else: verified full-rescan chain (+ separate-final-free fused normal)
// ---------------------------------------------------------------------------
extern "C" void kernel_launch(void* const* d_in, const int* in_sizes, int n_in,
                              void* d_out, int out_size, void* d_ws, size_t ws_size,
                              hipStream_t stream) {
    const float* gts     = (const float*)d_in[0];
    const float* preds   = (const float*)d_in[1];
    const float* normals = (const float*)d_in[2];
    float* out = (float*)d_out;

    char* ws = (char*)d_ws;
    float4* pkG  = (float4*)ws;
    float4* pkP  = (float4*)(ws + 262144);
    float4* pkGT = (float4*)(ws + 524288);
    float4* pkPT = (float4*)(ws + 786432);
    int* iS0 = (int*)(ws + 1048576);
    int* iS1 = iS0 + TOT;
    int* iS2 = iS1 + TOT;
    int* iF0 = iS2 + TOT;
    int* iF1 = iF0 + TOT;
    int* iF2 = iF1 + TOT;
    int* iF3 = iF2 + TOT;
    float* dS0 = (float*)(iF3 + TOT);
    float* dF0 = dS0 + TOT;
    float4* partials = (float4*)(dF0 + TOT);
    int* iS0T = (int*)((char*)partials + 256);
    int* iS1T = iS0T + TOT;
    int* iS2T = iS1T + TOT;
    int* iF0T = iS2T + TOT;
    int* iF1T = iF0T + TOT;
    int* iF2T = iF1T + TOT;
    size_t stripeOfs = (size_t)((char*)(iF2T + TOT) - ws);  // ~2.03 MB, aligned
    int2* stripes = (int2*)(ws + stripeOfs);
    size_t pairOfs = stripeOfs + (size_t)2 * TOT * 64 * sizeof(int2);
    float* pairG = (float*)(ws + pairOfs);
    float* pairP = pairG + (size_t)TOT * 8;
    size_t ctrOfs = pairOfs + (size_t)2 * TOT * 8 * sizeof(float);
    int* counter = (int*)(ws + ctrOfs);
    size_t need64 = ctrOfs + 256;                                          // ~19.9 MB
    size_t need16 = stripeOfs + (size_t)2 * TOT * 16 * sizeof(int2) + 256; // ~6.0 MB

    if (ws_size >= need64) {
        pack_kernel<64><<<(2 * TOT + 255) / 256, 256, 0, stream>>>(
            gts, preds, pkG, pkP, pkGT, pkPT, pairG, pairP, counter);
        round0_packed<<<2048, 256, 0, stream>>>(pkG, pkP, pairG, pairP,
            dS0, iS0, dF0, iF0, iS0T, iF0T, stripes);
        // roundR: 16 own-slots per block (verified 4-pt/wave shape)
        roundR_kernel<1, 64><<<2048, 256, 0, stream>>>(pkG, pkP, pkGT, pkPT, stripes,
            iS0, iS1, iS2, iF0, iF1, iF2,
            iS0T, iS1T, iS2T, iF0T, iF1T, iF2T,
            iS1, iF1, iS1T, iF1T, 1);
        roundR_kernel<2, 64><<<2048, 256, 0, stream>>>(pkG, pkP, pkGT, pkPT, stripes,
            iS0, iS1, iS2, iF0, iF1, iF2,
            iS0T, iS1T, iS2T, iF0T, iF1T, iF2T,
            iS2, iF2, iS2T, iF2T, 1);
        roundR_kernel<3, 64><<<1024, 256, 0, stream>>>(pkG, pkP, pkGT, pkPT, stripes,
            iS0, iS1, iS2, iF0, iF1, iF2,
            iS0T, iS1T, iS2T, iF0T, iF1T, iF2T,
            nullptr, iF3, nullptr, nullptr, 0);
    } else if (ws_size >= need16) {
        pack_kernel<16><<<(2 * TOT + 255) / 256, 256, 0, stream>>>(
            gts, preds, pkG, pkP, pkGT, pkPT, nullptr, nullptr, counter);
        round0_kernel<16><<<2048, 256, 0, stream>>>(pkG, pkP, dS0, iS0, dF0, iF0,
                                                    iS0T, iF0T, stripes);
        roundR_kernel<1, 16><<<2048, 256, 0, stream>>>(pkG, pkP, pkGT, pkPT, stripes,
            iS0, iS1, iS2, iF0, iF1, iF2,
            iS0T, iS1T, iS2T, iF0T, iF1T, iF2T,
            iS1, iF1, iS1T, iF1T, 1);
        roundR_kernel<2, 16><<<2048, 256, 0, stream>>>(pkG, pkP, pkGT, pkPT, stripes,
            iS0, iS1, iS2, iF0, iF1, iF2,
            iS0T, iS1T, iS2T, iF0T, iF1T, iF2T,
            iS2, iF2, iS2T, iF2T, 1);
        roundR_kernel<3, 16><<<1024, 256, 0, stream>>>(pkG, pkP, pkGT, pkPT, stripes,
            iS0, iS1, iS2, iF0, iF1, iF2,
            iS0T, iS1T, iS2T, iF0T, iF1T, iF2T,
            nullptr, iF3, nullptr, nullptr, 0);
    } else {
        pack_kernel<64><<<(2 * TOT + 255) / 256, 256, 0, stream>>>(
            gts, preds, pkG, pkP, pkGT, pkPT, nullptr, nullptr, counter);
        round_full_kernel<0><<<2048, 256, 0, stream>>>(pkG, pkP,
            nullptr, nullptr, nullptr, nullptr, nullptr, nullptr,
            dS0, iS0, dF0, iF0, 1);
        round_full_kernel<1><<<2048, 256, 0, stream>>>(pkG, pkP,
            iS0, nullptr, nullptr, iF0, nullptr, nullptr,
            nullptr, iS1, nullptr, iF1, 1);
        round_full_kernel<2><<<2048, 256, 0, stream>>>(pkG, pkP,
            iS0, iS1, nullptr, iF0, iF1, nullptr,
            nullptr, iS2, nullptr, iF2, 1);
        round_full_kernel<3><<<1024, 256, 0, stream>>>(pkG, pkP,
            iS0, iS1, iS2, iF0, iF1, iF2,
            nullptr, nullptr, nullptr, iF3, 0);
    }

    normal_kernel<<<16, 256, 0, stream>>>(preds, normals, dS0, dF0,
                                          iF0, iF1, iF2, iF3,
                                          partials, counter, out);
}